// Round 8
// baseline (32.048 us; speedup 1.0000x reference)
//
#include <hip/hip_runtime.h>

// Problem constants (match reference)
constexpr int B_ = 16, C_ = 80, H_ = 100, W_ = 100, N_ = 32;
constexpr int HW = H_ * W_;
constexpr int BN = B_ * N_;          // 512
constexpr float POS_THR = 0.3f;
constexpr int TPB = 1024;            // 16 waves/block, grid=512 -> 2 blocks/CU

__device__ __forceinline__ float rcpf(float x) { return __builtin_amdgcn_rcpf(x); }

// giou = inter/union + union/area_c - 1   (algebraic refactor of reference)
__device__ __forceinline__ float giou4(const float4 a,
                                       const float gx0, const float gy0,
                                       const float gx1, const float gy1,
                                       const float area_b) {
    float area_a = (a.z - a.x) * (a.w - a.y);
    float ltx = fmaxf(a.x, gx0), lty = fmaxf(a.y, gy0);
    float rbx = fminf(a.z, gx1), rby = fminf(a.w, gy1);
    float iw = fmaxf(rbx - ltx, 0.0f), ih = fmaxf(rby - lty, 0.0f);
    float inter = iw * ih;
    float uni = area_a + area_b - inter;
    float cx0 = fminf(a.x, gx0), cy0 = fminf(a.y, gy0);
    float cx1 = fmaxf(a.z, gx1), cy1 = fmaxf(a.w, gy1);
    float area_c = (cx1 - cx0) * (cy1 - cy0);   // cx1>=cx0, cy1>=cy0 always
    return inter * rcpf(uni) + uni * rcpf(area_c) - 1.0f;
}

// ws layout (floats):
//   [0..BN)      l1 partials     (distinct slot per bn)
//   [BN..2BN)    giou partials
//   [2BN..3BN)   cnt partials
//   [3BN..3BN+8) group tickets (uint, 64 arrivals each)
//   [3BN+8]      global ticket (uint, 8 arrivals)
//
// R2/R3/R6 post-mortem: a SINGLE hot ticket address takes 512 near-
// simultaneous RMWs -> 8-20us serialized tail. Two-level ticket tree keeps
// every address at <=64 arrivals (parallel across 8 addresses) -> ~1us tail.
// No __threadfence anywhere; release ordering = atomicExch publish +
// s_waitcnt vmcnt(0) + ticket RMW (return-value dependency orders levels).
__global__ __launch_bounds__(TPB, 8) void fused_kernel(
    const float* __restrict__ pred,   // [B,C,H,W,4]
    const float* __restrict__ gt,     // [B,N,4]
    const int*   __restrict__ labels, // [B,N]
    float* __restrict__ ws,
    float* __restrict__ out)
{
    const int bn   = blockIdx.x;
    const int lane = threadIdx.x & 63;
    const int wid  = threadIdx.x >> 6;

    const int b  = bn / N_;
    const int label = labels[bn];
    const float4 g4 = reinterpret_cast<const float4*>(gt)[bn];
    const float area_b = (g4.z - g4.x) * (g4.w - g4.y);
    const float4* __restrict__ base =
        reinterpret_cast<const float4*>(pred) + ((size_t)b * C_ + label) * HW;

    // Per-thread scan, unrolled x2. Ascending index order + strict > keeps
    // the earliest index within a thread.
    float best = -3.0f;   // GIoU >= -1 always
    int   bi   = HW;
    int i = threadIdx.x;
    for (; i + TPB < HW; i += 2 * TPB) {
        float4 a0 = base[i];
        float4 a1 = base[i + TPB];
        float g0 = giou4(a0, g4.x, g4.y, g4.z, g4.w, area_b);
        float g1 = giou4(a1, g4.x, g4.y, g4.z, g4.w, area_b);
        if (g0 > best) { best = g0; bi = i; }
        if (g1 > best) { best = g1; bi = i + TPB; }
    }
    if (i < HW) {
        float g = giou4(base[i], g4.x, g4.y, g4.z, g4.w, area_b);
        if (g > best) { best = g; bi = i; }
    }

    // Wave-64 reduce: (max value, min index on ties) == first-occurrence argmax.
    #pragma unroll
    for (int off = 32; off; off >>= 1) {
        float ov = __shfl_down(best, off, 64);
        int   oi = __shfl_down(bi,   off, 64);
        if (ov > best || (ov == best && oi < bi)) { best = ov; bi = oi; }
    }

    __shared__ float sv[16];
    __shared__ int   si[16];
    if (lane == 0) { sv[wid] = best; si[wid] = bi; }
    __syncthreads();

    if (wid != 0) return;   // waves 1..15 done

    // Wave 0 finishes: 16 per-wave candidates live in lanes 0..15.
    best = (lane < 16) ? sv[lane] : -3.0f;
    bi   = (lane < 16) ? si[lane] : HW;
    #pragma unroll
    for (int off = 8; off; off >>= 1) {
        float ov = __shfl_down(best, off, 16);
        int   oi = __shfl_down(bi,   off, 16);
        if (ov > best || (ov == best && oi < bi)) { best = ov; bi = oi; }
    }
    best = __shfl(best, 0, 64);
    bi   = __shfl(bi,   0, 64);

    float sl1 = 0.0f, sg = 0.0f, ct = 0.0f;
    if (best > POS_THR) {
        const int mi = bi / W_, mj = bi % W_;
        const int r0 = max(mi - 2, 0), r1 = min(mi + 1, H_ - 1);
        const int c0 = max(mj - 2, 0), c1 = min(mj + 1, W_ - 1);
        // Lanes 0..15 cover the (<=4)x(<=4) window in parallel.
        const int r = r0 + (lane >> 2);
        const int c = c0 + (lane & 3);
        if (lane < 16 && r <= r1 && c <= c1) {
            float4 a = base[r * W_ + c];
            float g = giou4(a, g4.x, g4.y, g4.z, g4.w, area_b);
            sl1 = 0.25f * (fabsf(a.x - g4.x) + fabsf(a.y - g4.y) +
                           fabsf(a.z - g4.z) + fabsf(a.w - g4.w));
            sg = 1.0f - g;
            ct = 1.0f;
        }
        #pragma unroll
        for (int off = 8; off; off >>= 1) {
            sl1 += __shfl_down(sl1, off, 16);
            sg  += __shfl_down(sg,  off, 16);
            ct  += __shfl_down(ct,  off, 16);
        }
    }

    // Publish + tree arrival.
    unsigned* tickets = (unsigned*)(ws + 3 * BN);   // [8 group][1 global]
    int last = 0;
    if (lane == 0) {
        atomicExch(&ws[bn], sl1);                  // coherent, distinct slots
        atomicExch(&ws[BN + bn], sg);
        atomicExch(&ws[2 * BN + bn], ct);
        asm volatile("s_waitcnt vmcnt(0)" ::: "memory");   // release
        unsigned og = atomicAdd(&tickets[bn >> 6], 1u);    // <=64 per address
        if (og == 63u) {                                   // last in group
            unsigned oglob = atomicAdd(&tickets[8], 1u);   // 8 arrivals total
            last = (oglob == 7u);
        }
    }
    last = __shfl(last, 0, 64);
    if (!last) return;

    // Global-last block: reduce all 512 partials (fixed order -> deterministic).
    float l1 = 0.0f, gi = 0.0f, cn = 0.0f;
    #pragma unroll
    for (int k = 0; k < BN / 64; ++k) {
        const int idx = lane + 64 * k;
        l1 += atomicAdd(&ws[idx], 0.0f);           // coherent reads,
        gi += atomicAdd(&ws[BN + idx], 0.0f);      // distinct addresses
        cn += atomicAdd(&ws[2 * BN + idx], 0.0f);
    }
    #pragma unroll
    for (int off = 32; off; off >>= 1) {
        l1 += __shfl_down(l1, off, 64);
        gi += __shfl_down(gi, off, 64);
        cn += __shfl_down(cn, off, 64);
    }
    if (lane == 0) {
        const float denom = fmaxf(cn, 1.0f);
        out[0] = l1 / denom + 2.0f * (gi / denom);
    }
}

extern "C" void kernel_launch(void* const* d_in, const int* in_sizes, int n_in,
                              void* d_out, int out_size, void* d_ws, size_t ws_size,
                              hipStream_t stream) {
    const float* pred   = (const float*)d_in[0];
    const float* gt     = (const float*)d_in[1];
    const int*   labels = (const int*)d_in[2];
    float* ws  = (float*)d_ws;
    float* out = (float*)d_out;

    // Zero the 9 ticket words every call (graph node; ws is never re-poisoned
    // and tickets from the previous replay would otherwise carry over).
    hipMemsetAsync(ws + 3 * BN, 0, 9 * sizeof(unsigned), stream);
    fused_kernel<<<BN, TPB, 0, stream>>>(pred, gt, labels, ws, out);
}

// Round 9
// 21.874 us; speedup vs baseline: 1.4651x; 1.4651x over previous
//
#include <hip/hip_runtime.h>

// Problem constants (match reference)
constexpr int B_ = 16, C_ = 80, H_ = 100, W_ = 100, N_ = 32;
constexpr int HW = H_ * W_;
constexpr int BN = B_ * N_;          // 512
constexpr float POS_THR = 0.3f;
constexpr int TPB = 1024;            // 16 waves/block, grid=512 -> 2 blocks/CU

__device__ __forceinline__ float rcpf(float x) { return __builtin_amdgcn_rcpf(x); }

// giou = inter/union + union/area_c - 1   (algebraic refactor of reference)
__device__ __forceinline__ float giou4(const float4 a,
                                       const float gx0, const float gy0,
                                       const float gx1, const float gy1,
                                       const float area_b) {
    float area_a = (a.z - a.x) * (a.w - a.y);
    float ltx = fmaxf(a.x, gx0), lty = fmaxf(a.y, gy0);
    float rbx = fminf(a.z, gx1), rby = fminf(a.w, gy1);
    float iw = fmaxf(rbx - ltx, 0.0f), ih = fmaxf(rby - lty, 0.0f);
    float inter = iw * ih;
    float uni = area_a + area_b - inter;
    float cx0 = fminf(a.x, gx0), cy0 = fminf(a.y, gy0);
    float cx1 = fmaxf(a.z, gx1), cy1 = fmaxf(a.w, gy1);
    float area_c = (cx1 - cx0) * (cy1 - cy0);   // cx1>=cx0, cy1>=cy0 always
    return inter * rcpf(uni) + uni * rcpf(area_c) - 1.0f;
}

// One block per (b, n): argmax of GIoU over the [H,W] class slice, then
// window sums by wave 0, one float4 partial {l1, giou, cnt, 0} per GT to ws.
// NOTE (R2/R3/R6/R7 lesson): every fused-finalize variant (fence / hot
// atomics / VGPR-capped exch / ticket tree) regressed 8-22us vs this
// two-kernel form — the 512-block arrival machinery costs more than the
// second dispatch. Keep two kernels.
__global__ __launch_bounds__(TPB) void per_gt_kernel(
    const float* __restrict__ pred,   // [B,C,H,W,4]
    const float* __restrict__ gt,     // [B,N,4]
    const int*   __restrict__ labels, // [B,N]
    float4* __restrict__ ws)          // [BN] packed partials
{
    const int bn = blockIdx.x;
    const int b  = bn / N_;
    const int label = labels[bn];
    const float4 g4 = reinterpret_cast<const float4*>(gt)[bn];
    const float area_b = (g4.z - g4.x) * (g4.w - g4.y);
    const float4* __restrict__ base =
        reinterpret_cast<const float4*>(pred) + ((size_t)b * C_ + label) * HW;

    // Per-thread scan. Ascending index order + strict > keeps the earliest
    // index within a thread.
    float best = -3.0f;   // GIoU >= -1 always
    int   bi   = HW;
    for (int i = threadIdx.x; i < HW; i += TPB) {
        float g = giou4(base[i], g4.x, g4.y, g4.z, g4.w, area_b);
        if (g > best) { best = g; bi = i; }
    }

    // Wave-64 reduce: (max value, min index on ties) == first-occurrence argmax.
    #pragma unroll
    for (int off = 32; off; off >>= 1) {
        float ov = __shfl_down(best, off, 64);
        int   oi = __shfl_down(bi,   off, 64);
        if (ov > best || (ov == best && oi < bi)) { best = ov; bi = oi; }
    }

    __shared__ float sv[16];
    __shared__ int   si[16];
    const int wid  = threadIdx.x >> 6;
    const int lane = threadIdx.x & 63;
    if (lane == 0) { sv[wid] = best; si[wid] = bi; }
    __syncthreads();

    if (wid != 0) return;   // waves 1..15 done

    // Wave 0 finishes: 16 per-wave candidates live in lanes 0..15.
    best = (lane < 16) ? sv[lane] : -3.0f;
    bi   = (lane < 16) ? si[lane] : HW;
    #pragma unroll
    for (int off = 8; off; off >>= 1) {
        float ov = __shfl_down(best, off, 16);
        int   oi = __shfl_down(bi,   off, 16);
        if (ov > best || (ov == best && oi < bi)) { best = ov; bi = oi; }
    }
    best = __shfl(best, 0, 64);
    bi   = __shfl(bi,   0, 64);

    float sl1 = 0.0f, sg = 0.0f, ct = 0.0f;
    if (best > POS_THR) {
        const int mi = bi / W_, mj = bi % W_;
        const int r0 = max(mi - 2, 0), r1 = min(mi + 1, H_ - 1);
        const int c0 = max(mj - 2, 0), c1 = min(mj + 1, W_ - 1);
        // Lanes 0..15 cover the (<=4)x(<=4) window in parallel.
        const int r = r0 + (lane >> 2);
        const int c = c0 + (lane & 3);
        if (lane < 16 && r <= r1 && c <= c1) {
            float4 a = base[r * W_ + c];
            float g = giou4(a, g4.x, g4.y, g4.z, g4.w, area_b);
            sl1 = 0.25f * (fabsf(a.x - g4.x) + fabsf(a.y - g4.y) +
                           fabsf(a.z - g4.z) + fabsf(a.w - g4.w));
            sg = 1.0f - g;
            ct = 1.0f;
        }
        #pragma unroll
        for (int off = 8; off; off >>= 1) {
            sl1 += __shfl_down(sl1, off, 16);
            sg  += __shfl_down(sg,  off, 16);
            ct  += __shfl_down(ct,  off, 16);
        }
    }
    if (lane == 0) {
        ws[bn] = make_float4(sl1, sg, ct, 0.0f);   // one coalesced 16B store
    }
}

// Single block reduces the 512 packed partials and writes the scalar loss.
__global__ __launch_bounds__(BN) void finalize_kernel(
    const float4* __restrict__ ws, float* __restrict__ out)
{
    const int t = threadIdx.x;
    const float4 p = ws[t];            // one coalesced 16B load per thread
    float l1 = p.x, gi = p.y, ct = p.z;
    #pragma unroll
    for (int off = 32; off; off >>= 1) {
        l1 += __shfl_down(l1, off, 64);
        gi += __shfl_down(gi, off, 64);
        ct += __shfl_down(ct, off, 64);
    }
    __shared__ float s0[8], s1[8], s2[8];
    const int wid = t >> 6;
    if ((t & 63) == 0) { s0[wid] = l1; s1[wid] = gi; s2[wid] = ct; }
    __syncthreads();
    if (t == 0) {
        float L = 0.0f, G = 0.0f, Cn = 0.0f;
        #pragma unroll
        for (int w = 0; w < BN / 64; ++w) { L += s0[w]; G += s1[w]; Cn += s2[w]; }
        const float denom = fmaxf(Cn, 1.0f);
        out[0] = L / denom + 2.0f * (G / denom);
    }
}

extern "C" void kernel_launch(void* const* d_in, const int* in_sizes, int n_in,
                              void* d_out, int out_size, void* d_ws, size_t ws_size,
                              hipStream_t stream) {
    const float* pred   = (const float*)d_in[0];
    const float* gt     = (const float*)d_in[1];
    const int*   labels = (const int*)d_in[2];
    float4* ws = (float4*)d_ws;
    float* out = (float*)d_out;

    per_gt_kernel<<<BN, TPB, 0, stream>>>(pred, gt, labels, ws);
    finalize_kernel<<<1, BN, 0, stream>>>(ws, out);
}

// Round 10
// 20.001 us; speedup vs baseline: 1.6023x; 1.0937x over previous
//
#include <hip/hip_runtime.h>

// Problem constants (match reference)
constexpr int B_ = 16, C_ = 80, H_ = 100, W_ = 100, N_ = 32;
constexpr int HW = H_ * W_;
constexpr int BN = B_ * N_;          // 512
constexpr float POS_THR = 0.3f;
constexpr int TPB = 1024;            // 16 waves/block, grid=512 -> 2 blocks/CU

__device__ __forceinline__ float rcpf(float x) { return __builtin_amdgcn_rcpf(x); }

// giou = inter/union + union/area_c - 1   (algebraic refactor of reference)
__device__ __forceinline__ float giou4(const float4 a,
                                       const float gx0, const float gy0,
                                       const float gx1, const float gy1,
                                       const float area_b) {
    float area_a = (a.z - a.x) * (a.w - a.y);
    float ltx = fmaxf(a.x, gx0), lty = fmaxf(a.y, gy0);
    float rbx = fminf(a.z, gx1), rby = fminf(a.w, gy1);
    float iw = fmaxf(rbx - ltx, 0.0f), ih = fmaxf(rby - lty, 0.0f);
    float inter = iw * ih;
    float uni = area_a + area_b - inter;
    float cx0 = fminf(a.x, gx0), cy0 = fminf(a.y, gy0);
    float cx1 = fmaxf(a.z, gx1), cy1 = fmaxf(a.w, gy1);
    float area_c = (cx1 - cx0) * (cy1 - cy0);   // cx1>=cx0, cy1>=cy0 always
    return inter * rcpf(uni) + uni * rcpf(area_c) - 1.0f;
}

// One block per (b, n): argmax of GIoU over the [H,W] class slice, then
// window sums by wave 0, one float4 partial {l1, giou, cnt, 0} per GT to ws.
// R9: XCD-pack swizzle — hardware round-robins consecutive blockIdx.x over
// 8 XCDs, so bn = (h&7)*64 + h>>3 puts each image's 32 blocks on ONE XCD;
// duplicate (b,label) slices (~17% of blocks) then hit XCD-local L2 instead
// of re-fetching HBM. Bijective on [0,512): only locality changes.
__global__ __launch_bounds__(TPB) void per_gt_kernel(
    const float* __restrict__ pred,   // [B,C,H,W,4]
    const float* __restrict__ gt,     // [B,N,4]
    const int*   __restrict__ labels, // [B,N]
    float4* __restrict__ ws)          // [BN] packed partials
{
    const int bn = ((blockIdx.x & 7) << 6) | (blockIdx.x >> 3);
    const int b  = bn / N_;
    const int label = labels[bn];
    const float4 g4 = reinterpret_cast<const float4*>(gt)[bn];
    const float area_b = (g4.z - g4.x) * (g4.w - g4.y);
    const float4* __restrict__ base =
        reinterpret_cast<const float4*>(pred) + ((size_t)b * C_ + label) * HW;

    // Per-thread scan. Ascending index order + strict > keeps the earliest
    // index within a thread.
    float best = -3.0f;   // GIoU >= -1 always
    int   bi   = HW;
    for (int i = threadIdx.x; i < HW; i += TPB) {
        float g = giou4(base[i], g4.x, g4.y, g4.z, g4.w, area_b);
        if (g > best) { best = g; bi = i; }
    }

    // Wave-64 reduce: (max value, min index on ties) == first-occurrence argmax.
    #pragma unroll
    for (int off = 32; off; off >>= 1) {
        float ov = __shfl_down(best, off, 64);
        int   oi = __shfl_down(bi,   off, 64);
        if (ov > best || (ov == best && oi < bi)) { best = ov; bi = oi; }
    }

    __shared__ float sv[16];
    __shared__ int   si[16];
    const int wid  = threadIdx.x >> 6;
    const int lane = threadIdx.x & 63;
    if (lane == 0) { sv[wid] = best; si[wid] = bi; }
    __syncthreads();

    if (wid != 0) return;   // waves 1..15 done

    // Wave 0 finishes: 16 per-wave candidates live in lanes 0..15.
    best = (lane < 16) ? sv[lane] : -3.0f;
    bi   = (lane < 16) ? si[lane] : HW;
    #pragma unroll
    for (int off = 8; off; off >>= 1) {
        float ov = __shfl_down(best, off, 16);
        int   oi = __shfl_down(bi,   off, 16);
        if (ov > best || (ov == best && oi < bi)) { best = ov; bi = oi; }
    }
    best = __shfl(best, 0, 64);
    bi   = __shfl(bi,   0, 64);

    float sl1 = 0.0f, sg = 0.0f, ct = 0.0f;
    if (best > POS_THR) {
        const int mi = bi / W_, mj = bi % W_;
        const int r0 = max(mi - 2, 0), r1 = min(mi + 1, H_ - 1);
        const int c0 = max(mj - 2, 0), c1 = min(mj + 1, W_ - 1);
        // Lanes 0..15 cover the (<=4)x(<=4) window in parallel.
        const int r = r0 + (lane >> 2);
        const int c = c0 + (lane & 3);
        if (lane < 16 && r <= r1 && c <= c1) {
            float4 a = base[r * W_ + c];
            float g = giou4(a, g4.x, g4.y, g4.z, g4.w, area_b);
            sl1 = 0.25f * (fabsf(a.x - g4.x) + fabsf(a.y - g4.y) +
                           fabsf(a.z - g4.z) + fabsf(a.w - g4.w));
            sg = 1.0f - g;
            ct = 1.0f;
        }
        #pragma unroll
        for (int off = 8; off; off >>= 1) {
            sl1 += __shfl_down(sl1, off, 16);
            sg  += __shfl_down(sg,  off, 16);
            ct  += __shfl_down(ct,  off, 16);
        }
    }
    if (lane == 0) {
        ws[bn] = make_float4(sl1, sg, ct, 0.0f);   // one coalesced 16B store
    }
}

// Single block reduces the 512 packed partials and writes the scalar loss.
__global__ __launch_bounds__(BN) void finalize_kernel(
    const float4* __restrict__ ws, float* __restrict__ out)
{
    const int t = threadIdx.x;
    const float4 p = ws[t];            // one coalesced 16B load per thread
    float l1 = p.x, gi = p.y, ct = p.z;
    #pragma unroll
    for (int off = 32; off; off >>= 1) {
        l1 += __shfl_down(l1, off, 64);
        gi += __shfl_down(gi, off, 64);
        ct += __shfl_down(ct, off, 64);
    }
    __shared__ float s0[8], s1[8], s2[8];
    const int wid = t >> 6;
    if ((t & 63) == 0) { s0[wid] = l1; s1[wid] = gi; s2[wid] = ct; }
    __syncthreads();
    if (t == 0) {
        float L = 0.0f, G = 0.0f, Cn = 0.0f;
        #pragma unroll
        for (int w = 0; w < BN / 64; ++w) { L += s0[w]; G += s1[w]; Cn += s2[w]; }
        const float denom = fmaxf(Cn, 1.0f);
        out[0] = L / denom + 2.0f * (G / denom);
    }
}

extern "C" void kernel_launch(void* const* d_in, const int* in_sizes, int n_in,
                              void* d_out, int out_size, void* d_ws, size_t ws_size,
                              hipStream_t stream) {
    const float* pred   = (const float*)d_in[0];
    const float* gt     = (const float*)d_in[1];
    const int*   labels = (const int*)d_in[2];
    float4* ws = (float4*)d_ws;
    float* out = (float*)d_out;

    per_gt_kernel<<<BN, TPB, 0, stream>>>(pred, gt, labels, ws);
    finalize_kernel<<<1, BN, 0, stream>>>(ws, out);
}